// Round 2
// baseline (170.298 us; speedup 1.0000x reference)
//
#include <hip/hip_runtime.h>
#include <math.h>

#define B 8
#define C 64
#define CI 32
#define N 2304        // 48*48
#define NB 4096       // sort pad
#define NT 36         // tiles of 64
#define NTOT (B*N)    // 18432
#define BN_EPS 1e-5

// ---- workspace layout (float offsets) ----
#define OFF_GX   0                      // [B][N][CI]
#define OFF_A    (OFF_GX + B*N*CI)      // [B][N]
#define OFF_C    (OFF_A + B*N)          // [B][N]
#define OFF_SC   (OFF_C + B*N)          // [B][N] sorted desc
#define OFF_SIDX (OFF_SC + B*N)         // [B][N] int
#define OFF_PLOC (OFF_SIDX + B*N)       // [B][N][64] exclusive in-tile prefix (g | c*g)
#define OFF_TOT  (OFF_PLOC + B*N*64)    // [B][NT][64] tile totals
#define OFF_STAT (OFF_TOT + B*NT*64)    // double[128]: sum[64], sumsq[64]

// ------------------------------------------------------------------
// K1: g_x[b,n,i] = g_w[i,:]·x[b,:,n] + g_b[i]
//     a[b,n] = tw·x[b,:,n] + tb   (tw[c]=Σ_i cp_wt[i] th_w[i,c])
//     c[b,n] = pw·x[b,:,n] + pb
__global__ __launch_bounds__(256) void k_proj(
    const float* __restrict__ x,
    const float* __restrict__ g_w, const float* __restrict__ g_b,
    const float* __restrict__ th_w, const float* __restrict__ th_b,
    const float* __restrict__ ph_w, const float* __restrict__ ph_b,
    const float* __restrict__ cp_wt, const float* __restrict__ cp_wp,
    float* __restrict__ ws)
{
    __shared__ float gw[CI*C];      // [i][c]
    __shared__ float tw[C], pw[C];
    __shared__ float gb[CI];
    __shared__ float tpb[2];
    const int tid = threadIdx.x;
    const int blk = blockIdx.x;     // b*9 + ntile
    const int b  = blk / 9;
    const int n0 = (blk % 9) * 256;

    for (int i = tid; i < CI*C; i += 256) gw[i] = g_w[i];
    if (tid < C) {
        float s = 0.f;
        for (int i = 0; i < CI; i++) s += cp_wt[i] * th_w[i*C + tid];
        tw[tid] = s;
    } else if (tid < 2*C) {
        int c = tid - C; float s = 0.f;
        for (int i = 0; i < CI; i++) s += cp_wp[i] * ph_w[i*C + c];
        pw[c] = s;
    } else if (tid < 2*C + CI) {
        gb[tid - 2*C] = g_b[tid - 2*C];
    } else if (tid == 2*C + CI) {
        float s = 0.f; for (int i = 0; i < CI; i++) s += cp_wt[i]*th_b[i]; tpb[0] = s;
    } else if (tid == 2*C + CI + 1) {
        float s = 0.f; for (int i = 0; i < CI; i++) s += cp_wp[i]*ph_b[i]; tpb[1] = s;
    }
    if (blk == 0 && tid < 128) ((double*)(ws + OFF_STAT))[tid] = 0.0;  // zero BN stats each call
    __syncthreads();

    const int n = n0 + tid;
    float accg[CI];
    #pragma unroll
    for (int i = 0; i < CI; i++) accg[i] = 0.f;
    float aa = 0.f, cc = 0.f;
    const float* xb = x + (size_t)b*C*N + n;
    #pragma unroll 4
    for (int c = 0; c < C; c++) {
        float xv = xb[(size_t)c*N];            // coalesced: lanes = consecutive n
        aa += tw[c]*xv;  cc += pw[c]*xv;
        #pragma unroll
        for (int i = 0; i < CI; i++) accg[i] += gw[i*C + c]*xv;   // uniform LDS broadcast
    }
    float* gx = ws + OFF_GX + ((size_t)(b*N + n))*CI;
    #pragma unroll
    for (int i = 0; i < CI; i++) accg[i] += gb[i];
    #pragma unroll
    for (int i = 0; i < CI; i += 4)
        *(float4*)(gx + i) = make_float4(accg[i], accg[i+1], accg[i+2], accg[i+3]);
    ws[OFF_A + b*N + n] = aa + tpb[0];
    ws[OFF_C + b*N + n] = cc + tpb[1];
}

// ------------------------------------------------------------------
// K2: per-batch bitonic sort of c (descending) with indices, padded to 4096
__global__ __launch_bounds__(1024) void k_sort(float* __restrict__ ws)
{
    __shared__ float sv[NB];
    __shared__ int   si[NB];
    const int tid = threadIdx.x;
    const int b = blockIdx.x;
    const float* cb = ws + OFF_C + b*N;
    for (int i = tid; i < NB; i += 1024) { sv[i] = (i < N) ? cb[i] : -3.402823466e38f; si[i] = i; }
    for (int k = 2; k <= NB; k <<= 1) {
        for (int j = k >> 1; j > 0; j >>= 1) {
            __syncthreads();
            for (int i = tid; i < NB; i += 1024) {
                int ixj = i ^ j;
                if (ixj > i) {
                    float v0 = sv[i], v1 = sv[ixj];
                    bool desc = ((i & k) == 0);
                    if ((v0 < v1) == desc) {         // descending segments
                        sv[i] = v1; sv[ixj] = v0;
                        int t = si[i]; si[i] = si[ixj]; si[ixj] = t;
                    }
                }
            }
        }
    }
    __syncthreads();
    float* sc = ws + OFF_SC + b*N;
    int*   sx = (int*)(ws + OFF_SIDX) + b*N;
    for (int i = tid; i < N; i += 1024) { sc[i] = sv[i]; sx[i] = si[i]; }
}

// ------------------------------------------------------------------
// K3: per (batch, tile of 64 sorted positions): exclusive in-tile prefix of
//     [g[m,i] ; c_m*g[m,i]] (64 channels), + tile totals.
__global__ __launch_bounds__(64) void k_prefix(float* __restrict__ ws)
{
    __shared__ int   sidx[64];
    __shared__ float scv[64];
    const int tid = threadIdx.x;          // channel 0..63
    const int blk = blockIdx.x;           // b*NT + t
    const int b = blk / NT, t = blk % NT;
    const int k0 = t * 64;
    sidx[tid] = ((const int*)(ws + OFF_SIDX))[b*N + k0 + tid];
    scv[tid]  = ws[OFF_SC + b*N + k0 + tid];
    __syncthreads();
    const float* gx = ws + OFF_GX + (size_t)b*N*CI;
    float* pl = ws + OFF_PLOC + ((size_t)b*N + k0)*64;
    const int  ch   = tid & 31;
    const bool isCG = tid >= 32;
    float acc = 0.f;
    #pragma unroll
    for (int k = 0; k < 64; k++) {
        int m = sidx[k];                               // uniform
        float gval = gx[(size_t)m*CI + ch];            // 128B gather, 2-way broadcast
        float v = isCG ? gval * scv[k] : gval;
        pl[(size_t)k*64 + tid] = acc;                  // exclusive prefix
        acc += v;
    }
    ws[OFF_TOT + ((size_t)b*NT + t)*64 + tid] = acc;
}

// ------------------------------------------------------------------
// shared helper: stage sorted-c + tile-offset scan, recompute y for a
// 64-position tile into LDS. Block = 256 thr: p=tid&63, ig=tid>>6 (8 ch each).
__device__ __forceinline__ void stage_and_y(
    const float* __restrict__ ws, int b, int tile,
    float* sc_lds, float* offs_lds /*(NT+1)*64*/, float* y_lds /*[64][33]*/)
{
    const int tid = threadIdx.x;
    const float* sc = ws + OFF_SC + b*N;
    for (int i = tid; i < N; i += 256) sc_lds[i] = sc[i];
    if (tid < 64) {                                    // exclusive scan of tile totals
        const float* tot = ws + OFF_TOT + (size_t)b*NT*64 + tid;
        float acc = 0.f;
        for (int t = 0; t < NT; t++) { offs_lds[t*64 + tid] = acc; acc += tot[(size_t)t*64]; }
        offs_lds[NT*64 + tid] = acc;
    }
    __syncthreads();

    const int p = tid & 63, ig = tid >> 6;
    const int n = tile*64 + p;
    const float an = ws[OFF_A + b*N + n];
    const float thr = -an;
    int lo = 0, hi = N;                                // count of sc[] > thr (desc order)
    while (lo < hi) { int mid = (lo + hi) >> 1; if (sc_lds[mid] > thr) lo = mid + 1; else hi = mid; }
    const int k = lo, kt = k >> 6;
    const float* pl = ws + OFF_PLOC + ((size_t)b*N + k)*64;
    const float inv_n = 1.0f / (float)N;
    #pragma unroll
    for (int q = 0; q < 8; q++) {
        int i = ig*8 + q;
        float plg = (k < N) ? pl[i]      : 0.f;
        float plc = (k < N) ? pl[i + 32] : 0.f;
        float Pg = offs_lds[kt*64 + i]      + plg;
        float Pc = offs_lds[kt*64 + i + 32] + plc;
        y_lds[p*33 + i] = inv_n * (an * Pg + Pc);
    }
}

// ------------------------------------------------------------------
// K4: BN batch stats: wy = W·y + W_b, accumulate Σwy, Σwy² per channel
// (double, wave-reduced, 128 global f64 atomics per block).
__global__ __launch_bounds__(256) void k_stats(
    const float* __restrict__ W_w, const float* __restrict__ W_b,
    float* __restrict__ ws)
{
    __shared__ float sc_lds[N];
    __shared__ float offs_lds[(NT+1)*64];
    __shared__ float y_lds[64*33];
    __shared__ float Wl[C*CI];
    const int tid = threadIdx.x;
    const int blk = blockIdx.x;
    const int b = blk / NT, tile = blk % NT;
    for (int i = tid; i < C*CI; i += 256) Wl[i] = W_w[i];
    stage_and_y(ws, b, tile, sc_lds, offs_lds, y_lds);
    __syncthreads();

    const int p = tid & 63, cg = tid >> 6, lane = tid & 63;
    double* stats = (double*)(ws + OFF_STAT);
    for (int q = 0; q < 16; q++) {
        int c = cg*16 + q;
        float wyv = W_b[c];
        #pragma unroll
        for (int i = 0; i < CI; i++) wyv += Wl[c*CI + i] * y_lds[p*33 + i];
        double s = (double)wyv, sq = (double)wyv * (double)wyv;
        #pragma unroll
        for (int off = 32; off >= 1; off >>= 1) {
            s  += __shfl_xor(s,  off, 64);
            sq += __shfl_xor(sq, off, 64);
        }
        if (lane == 0) { atomicAdd(&stats[c], s); atomicAdd(&stats[64 + c], sq); }
    }
}

// ------------------------------------------------------------------
// K5: finalize: recompute y -> wy, apply BN (scale/shift from stats), +x.
__global__ __launch_bounds__(256) void k_final(
    const float* __restrict__ x,
    const float* __restrict__ W_w, const float* __restrict__ W_b,
    const float* __restrict__ bn_g, const float* __restrict__ bn_b,
    const float* __restrict__ ws, float* __restrict__ out)
{
    __shared__ float sc_lds[N];
    __shared__ float offs_lds[(NT+1)*64];
    __shared__ float y_lds[64*33];
    __shared__ float Wl[C*CI];
    __shared__ float scale[C], shift[C];
    const int tid = threadIdx.x;
    const int blk = blockIdx.x;
    const int b = blk / NT, tile = blk % NT;
    for (int i = tid; i < C*CI; i += 256) Wl[i] = W_w[i];
    if (tid < C) {
        const double* stats = (const double*)(ws + OFF_STAT);
        double mean = stats[tid] / (double)NTOT;
        double var  = stats[64 + tid] / (double)NTOT - mean*mean;
        float rs = (float)(1.0 / sqrt(var + BN_EPS));
        float s  = bn_g[tid] * rs;
        scale[tid] = s;
        shift[tid] = bn_b[tid] - (float)mean * s;
    }
    stage_and_y(ws, b, tile, sc_lds, offs_lds, y_lds);
    __syncthreads();

    const int p = tid & 63, cg = tid >> 6;
    const int n = tile*64 + p;
    const float* xb = x   + (size_t)b*C*N + n;
    float*       ob = out + (size_t)b*C*N + n;
    for (int q = 0; q < 16; q++) {
        int c = cg*16 + q;
        float wyv = W_b[c];
        #pragma unroll
        for (int i = 0; i < CI; i++) wyv += Wl[c*CI + i] * y_lds[p*33 + i];
        ob[(size_t)c*N] = wyv * scale[c] + shift[c] + xb[(size_t)c*N];   // coalesced
    }
}

// ------------------------------------------------------------------
extern "C" void kernel_launch(void* const* d_in, const int* in_sizes, int n_in,
                              void* d_out, int out_size, void* d_ws, size_t ws_size,
                              hipStream_t stream)
{
    const float* x     = (const float*)d_in[0];
    const float* g_w   = (const float*)d_in[1];
    const float* g_b   = (const float*)d_in[2];
    const float* th_w  = (const float*)d_in[3];
    const float* th_b  = (const float*)d_in[4];
    const float* ph_w  = (const float*)d_in[5];
    const float* ph_b  = (const float*)d_in[6];
    const float* cp_wt = (const float*)d_in[7];
    const float* cp_wp = (const float*)d_in[8];
    const float* W_w   = (const float*)d_in[9];
    const float* W_b   = (const float*)d_in[10];
    const float* bn_g  = (const float*)d_in[11];
    const float* bn_b  = (const float*)d_in[12];
    float* ws  = (float*)d_ws;
    float* out = (float*)d_out;

    hipLaunchKernelGGL(k_proj,   dim3(B*9),  dim3(256),  0, stream,
                       x, g_w, g_b, th_w, th_b, ph_w, ph_b, cp_wt, cp_wp, ws);
    hipLaunchKernelGGL(k_sort,   dim3(B),    dim3(1024), 0, stream, ws);
    hipLaunchKernelGGL(k_prefix, dim3(B*NT), dim3(64),   0, stream, ws);
    hipLaunchKernelGGL(k_stats,  dim3(B*NT), dim3(256),  0, stream, W_w, W_b, ws);
    hipLaunchKernelGGL(k_final,  dim3(B*NT), dim3(256),  0, stream,
                       x, W_w, W_b, bn_g, bn_b, ws, out);
}

// Round 3
// 169.673 us; speedup vs baseline: 1.0037x; 1.0037x over previous
//
#include <hip/hip_runtime.h>
#include <math.h>

#define B 8
#define C 64
#define CI 32
#define N 2304        // 48*48
#define NT 36         // tiles of 64
#define NTOT (B*N)    // 18432
#define BN_EPS 1e-5

// ---- workspace layout (float offsets) ----
#define OFF_GX   0                      // [B][N][CI]
#define OFF_A    (OFF_GX + B*N*CI)      // [B][N]
#define OFF_C    (OFF_A + B*N)          // [B][N]
#define OFF_SC   (OFF_C + B*N)          // [B][N] sorted desc
#define OFF_SIDX (OFF_SC + B*N)         // [B][N] int
#define OFF_PLOC (OFF_SIDX + B*N)       // [B][N][64] exclusive in-tile prefix (g | c*g)
#define OFF_TOT  (OFF_PLOC + B*N*64)    // [B][NT][64] tile totals
#define OFF_STAT (OFF_TOT + B*NT*64)    // double[128]: sum[64], sumsq[64]

// ------------------------------------------------------------------
// K1: g_x[b,n,i] = g_w[i,:]·x[b,:,n] + g_b[i]
//     a[b,n] = tw·x[b,:,n] + tb   (tw[c]=Σ_i cp_wt[i] th_w[i,c])
//     c[b,n] = pw·x[b,:,n] + pb
__global__ __launch_bounds__(256) void k_proj(
    const float* __restrict__ x,
    const float* __restrict__ g_w, const float* __restrict__ g_b,
    const float* __restrict__ th_w, const float* __restrict__ th_b,
    const float* __restrict__ ph_w, const float* __restrict__ ph_b,
    const float* __restrict__ cp_wt, const float* __restrict__ cp_wp,
    float* __restrict__ ws)
{
    __shared__ float gw[CI*C];      // [i][c] (row-major, c contiguous)
    __shared__ float tw[C], pw[C];
    __shared__ float gb[CI];
    __shared__ float tpb[2];
    const int tid = threadIdx.x;
    const int blk = blockIdx.x;     // b*9 + ntile
    const int b  = blk / 9;
    const int n0 = (blk % 9) * 256;

    for (int i = tid; i < CI*C; i += 256) gw[i] = g_w[i];
    if (tid < C) {
        float s = 0.f;
        for (int i = 0; i < CI; i++) s += cp_wt[i] * th_w[i*C + tid];
        tw[tid] = s;
    } else if (tid < 2*C) {
        int c = tid - C; float s = 0.f;
        for (int i = 0; i < CI; i++) s += cp_wp[i] * ph_w[i*C + c];
        pw[c] = s;
    } else if (tid < 2*C + CI) {
        gb[tid - 2*C] = g_b[tid - 2*C];
    } else if (tid == 2*C + CI) {
        float s = 0.f; for (int i = 0; i < CI; i++) s += cp_wt[i]*th_b[i]; tpb[0] = s;
    } else if (tid == 2*C + CI + 1) {
        float s = 0.f; for (int i = 0; i < CI; i++) s += cp_wp[i]*ph_b[i]; tpb[1] = s;
    }
    if (blk == 0 && tid < 128) ((double*)(ws + OFF_STAT))[tid] = 0.0;  // zero BN stats each call
    __syncthreads();

    const int n = n0 + tid;
    float accg[CI];
    #pragma unroll
    for (int i = 0; i < CI; i++) accg[i] = 0.f;
    float aa = 0.f, cc = 0.f;
    const float* xb = x + (size_t)b*C*N + n;
    #pragma unroll 4
    for (int c4 = 0; c4 < C; c4 += 4) {
        // 4 coalesced x loads (lanes = consecutive n)
        float xv0 = xb[(size_t)(c4+0)*N];
        float xv1 = xb[(size_t)(c4+1)*N];
        float xv2 = xb[(size_t)(c4+2)*N];
        float xv3 = xb[(size_t)(c4+3)*N];
        float4 t4 = *(const float4*)(tw + c4);
        float4 p4 = *(const float4*)(pw + c4);
        aa += t4.x*xv0 + t4.y*xv1 + t4.z*xv2 + t4.w*xv3;
        cc += p4.x*xv0 + p4.y*xv1 + p4.z*xv2 + p4.w*xv3;
        #pragma unroll
        for (int i = 0; i < CI; i++) {
            float4 g4 = *(const float4*)(gw + i*C + c4);   // b128 broadcast
            accg[i] += g4.x*xv0 + g4.y*xv1 + g4.z*xv2 + g4.w*xv3;
        }
    }
    float* gx = ws + OFF_GX + ((size_t)(b*N + n))*CI;
    #pragma unroll
    for (int i = 0; i < CI; i++) accg[i] += gb[i];
    #pragma unroll
    for (int i = 0; i < CI; i += 4)
        *(float4*)(gx + i) = make_float4(accg[i], accg[i+1], accg[i+2], accg[i+3]);
    ws[OFF_A + b*N + n] = aa + tpb[0];
    ws[OFF_C + b*N + n] = cc + tpb[1];
}

// ------------------------------------------------------------------
// K2: rank-by-counting sort (exact, deterministic). rank(m) =
//   #{j: c_j > c_m} + #{j<m: c_j == c_m}  -- strict total order -> permutation.
// Scatter directly into sorted arrays. 42.5M compares total, VALU-trivial.
__global__ __launch_bounds__(256) void k_rank(float* __restrict__ ws)
{
    __shared__ float cv[N];
    const int tid = threadIdx.x;
    const int blk = blockIdx.x;      // b*9 + mtile
    const int b = blk / 9;
    const float* cb = ws + OFF_C + b*N;
    for (int i = tid; i < N; i += 256) cv[i] = cb[i];
    __syncthreads();
    const int m = (blk % 9) * 256 + tid;
    const float my = cv[m];
    int rank = 0;
    #pragma unroll 8
    for (int j = 0; j < N; j++) {
        float v = cv[j];                       // wave-uniform LDS broadcast
        rank += ((v > my) || (v == my && j < m)) ? 1 : 0;
    }
    ws[OFF_SC + b*N + rank] = my;
    ((int*)(ws + OFF_SIDX))[b*N + rank] = m;
}

// ------------------------------------------------------------------
// K3: per (batch, tile of 64 sorted positions): exclusive in-tile prefix of
//     [g[m,i] ; c_m*g[m,i]] (64 channels), + tile totals.
__global__ __launch_bounds__(64) void k_prefix(float* __restrict__ ws)
{
    __shared__ int   sidx[64];
    __shared__ float scv[64];
    const int tid = threadIdx.x;          // channel 0..63
    const int blk = blockIdx.x;           // b*NT + t
    const int b = blk / NT, t = blk % NT;
    const int k0 = t * 64;
    sidx[tid] = ((const int*)(ws + OFF_SIDX))[b*N + k0 + tid];
    scv[tid]  = ws[OFF_SC + b*N + k0 + tid];
    __syncthreads();
    const float* gx = ws + OFF_GX + (size_t)b*N*CI;
    float* pl = ws + OFF_PLOC + ((size_t)b*N + k0)*64;
    const int  ch   = tid & 31;
    const bool isCG = tid >= 32;
    float acc = 0.f;
    #pragma unroll
    for (int k = 0; k < 64; k++) {
        int m = sidx[k];                               // uniform
        float gval = gx[(size_t)m*CI + ch];            // 128B gather, 2-way broadcast
        float v = isCG ? gval * scv[k] : gval;
        pl[(size_t)k*64 + tid] = acc;                  // exclusive prefix
        acc += v;
    }
    ws[OFF_TOT + ((size_t)b*NT + t)*64 + tid] = acc;
}

// ------------------------------------------------------------------
// shared helper: stage sorted-c + tile-offset scan, recompute y for a
// 64-position tile into LDS. Block = 256 thr: p=tid&63, ig=tid>>6 (8 ch each).
__device__ __forceinline__ void stage_and_y(
    const float* __restrict__ ws, int b, int tile,
    float* sc_lds, float* offs_lds /*(NT+1)*64*/, float* y_lds /*[64][33]*/)
{
    const int tid = threadIdx.x;
    const float* sc = ws + OFF_SC + b*N;
    for (int i = tid; i < N; i += 256) sc_lds[i] = sc[i];
    if (tid < 64) {                                    // exclusive scan of tile totals
        const float* tot = ws + OFF_TOT + (size_t)b*NT*64 + tid;
        float acc = 0.f;
        for (int t = 0; t < NT; t++) { offs_lds[t*64 + tid] = acc; acc += tot[(size_t)t*64]; }
        offs_lds[NT*64 + tid] = acc;
    }
    __syncthreads();

    const int p = tid & 63, ig = tid >> 6;
    const int n = tile*64 + p;
    const float an = ws[OFF_A + b*N + n];
    const float thr = -an;
    int lo = 0, hi = N;                                // count of sc[] > thr (desc order)
    while (lo < hi) { int mid = (lo + hi) >> 1; if (sc_lds[mid] > thr) lo = mid + 1; else hi = mid; }
    const int k = lo, kt = k >> 6;
    const float* pl = ws + OFF_PLOC + ((size_t)b*N + k)*64;
    const float inv_n = 1.0f / (float)N;
    #pragma unroll
    for (int q = 0; q < 8; q++) {
        int i = ig*8 + q;
        float plg = (k < N) ? pl[i]      : 0.f;
        float plc = (k < N) ? pl[i + 32] : 0.f;
        float Pg = offs_lds[kt*64 + i]      + plg;
        float Pc = offs_lds[kt*64 + i + 32] + plc;
        y_lds[p*33 + i] = inv_n * (an * Pg + Pc);
    }
}

// ------------------------------------------------------------------
// K4: BN batch stats: wy = W·y + W_b, accumulate Σwy, Σwy² per channel
// (double, wave-reduced, 128 global f64 atomics per block).
__global__ __launch_bounds__(256) void k_stats(
    const float* __restrict__ W_w, const float* __restrict__ W_b,
    float* __restrict__ ws)
{
    __shared__ float sc_lds[N];
    __shared__ float offs_lds[(NT+1)*64];
    __shared__ float y_lds[64*33];
    __shared__ float Wl[C*CI];
    const int tid = threadIdx.x;
    const int blk = blockIdx.x;
    const int b = blk / NT, tile = blk % NT;
    for (int i = tid; i < C*CI; i += 256) Wl[i] = W_w[i];
    stage_and_y(ws, b, tile, sc_lds, offs_lds, y_lds);
    __syncthreads();

    const int p = tid & 63, cg = tid >> 6, lane = tid & 63;
    double* stats = (double*)(ws + OFF_STAT);
    for (int q = 0; q < 16; q++) {
        int c = cg*16 + q;
        float wyv = W_b[c];
        #pragma unroll
        for (int i4 = 0; i4 < CI; i4 += 4) {
            float4 w4 = *(const float4*)(Wl + c*CI + i4);   // b128 broadcast
            wyv += w4.x*y_lds[p*33 + i4]   + w4.y*y_lds[p*33 + i4+1]
                 + w4.z*y_lds[p*33 + i4+2] + w4.w*y_lds[p*33 + i4+3];
        }
        double s = (double)wyv, sq = (double)wyv * (double)wyv;
        #pragma unroll
        for (int off = 32; off >= 1; off >>= 1) {
            s  += __shfl_xor(s,  off, 64);
            sq += __shfl_xor(sq, off, 64);
        }
        if (lane == 0) { atomicAdd(&stats[c], s); atomicAdd(&stats[64 + c], sq); }
    }
}

// ------------------------------------------------------------------
// K5: finalize: recompute y -> wy, apply BN (scale/shift from stats), +x.
__global__ __launch_bounds__(256) void k_final(
    const float* __restrict__ x,
    const float* __restrict__ W_w, const float* __restrict__ W_b,
    const float* __restrict__ bn_g, const float* __restrict__ bn_b,
    const float* __restrict__ ws, float* __restrict__ out)
{
    __shared__ float sc_lds[N];
    __shared__ float offs_lds[(NT+1)*64];
    __shared__ float y_lds[64*33];
    __shared__ float Wl[C*CI];
    __shared__ float scale[C], shift[C];
    const int tid = threadIdx.x;
    const int blk = blockIdx.x;
    const int b = blk / NT, tile = blk % NT;
    for (int i = tid; i < C*CI; i += 256) Wl[i] = W_w[i];
    if (tid < C) {
        const double* stats = (const double*)(ws + OFF_STAT);
        double mean = stats[tid] / (double)NTOT;
        double var  = stats[64 + tid] / (double)NTOT - mean*mean;
        float rs = (float)(1.0 / sqrt(var + BN_EPS));
        float s  = bn_g[tid] * rs;
        scale[tid] = s;
        shift[tid] = bn_b[tid] - (float)mean * s;
    }
    stage_and_y(ws, b, tile, sc_lds, offs_lds, y_lds);
    __syncthreads();

    const int p = tid & 63, cg = tid >> 6;
    const int n = tile*64 + p;
    const float* xb = x   + (size_t)b*C*N + n;
    float*       ob = out + (size_t)b*C*N + n;
    for (int q = 0; q < 16; q++) {
        int c = cg*16 + q;
        float wyv = W_b[c];
        #pragma unroll
        for (int i4 = 0; i4 < CI; i4 += 4) {
            float4 w4 = *(const float4*)(Wl + c*CI + i4);   // b128 broadcast
            wyv += w4.x*y_lds[p*33 + i4]   + w4.y*y_lds[p*33 + i4+1]
                 + w4.z*y_lds[p*33 + i4+2] + w4.w*y_lds[p*33 + i4+3];
        }
        ob[(size_t)c*N] = wyv * scale[c] + shift[c] + xb[(size_t)c*N];   // coalesced
    }
}

// ------------------------------------------------------------------
extern "C" void kernel_launch(void* const* d_in, const int* in_sizes, int n_in,
                              void* d_out, int out_size, void* d_ws, size_t ws_size,
                              hipStream_t stream)
{
    const float* x     = (const float*)d_in[0];
    const float* g_w   = (const float*)d_in[1];
    const float* g_b   = (const float*)d_in[2];
    const float* th_w  = (const float*)d_in[3];
    const float* th_b  = (const float*)d_in[4];
    const float* ph_w  = (const float*)d_in[5];
    const float* ph_b  = (const float*)d_in[6];
    const float* cp_wt = (const float*)d_in[7];
    const float* cp_wp = (const float*)d_in[8];
    const float* W_w   = (const float*)d_in[9];
    const float* W_b   = (const float*)d_in[10];
    const float* bn_g  = (const float*)d_in[11];
    const float* bn_b  = (const float*)d_in[12];
    float* ws  = (float*)d_ws;
    float* out = (float*)d_out;

    hipLaunchKernelGGL(k_proj,   dim3(B*9),  dim3(256), 0, stream,
                       x, g_w, g_b, th_w, th_b, ph_w, ph_b, cp_wt, cp_wp, ws);
    hipLaunchKernelGGL(k_rank,   dim3(B*9),  dim3(256), 0, stream, ws);
    hipLaunchKernelGGL(k_prefix, dim3(B*NT), dim3(64),  0, stream, ws);
    hipLaunchKernelGGL(k_stats,  dim3(B*NT), dim3(256), 0, stream, W_w, W_b, ws);
    hipLaunchKernelGGL(k_final,  dim3(B*NT), dim3(256), 0, stream,
                       x, W_w, W_b, bn_g, bn_b, ws, out);
}

// Round 6
// 116.388 us; speedup vs baseline: 1.4632x; 1.4578x over previous
//
#include <hip/hip_runtime.h>
#include <math.h>

#define B 8
#define C 64
#define CI 32
#define N 2304        // 48*48
#define NT 36         // tiles of 64
#define NTOT (B*N)    // 18432
#define BN_EPS 1e-5

// ---- workspace layout (float offsets) ----
#define OFF_GX   0                      // [B][N][CI]  (k_proj: g_x; after k_stats: y)
#define OFF_A    (OFF_GX + B*N*CI)      // [B][N]
#define OFF_C    (OFF_A + B*N)          // [B][N]
#define OFF_SC   (OFF_C + B*N)          // [B][N] sorted desc
#define OFF_SIDX (OFF_SC + B*N)         // [B][N] int
#define OFF_PLOC (OFF_SIDX + B*N)       // [B][N][64] exclusive in-tile prefix (g | c*g)
#define OFF_TOT  (OFF_PLOC + B*N*64)    // [B][NT][64] tile totals
#define OFF_STAT (OFF_TOT + B*NT*64)    // double[128]: sum[64], sumsq[64]

// ------------------------------------------------------------------
// K1: g_x[b,n,i] = g_w[i,:]·x[b,:,n] + g_b[i]
//     a[b,n] = tw·x[b,:,n] + tb   (tw[c]=Σ_i cp_wt[i] th_w[i,c])
//     c[b,n] = pw·x[b,:,n] + pb
__global__ __launch_bounds__(256) void k_proj(
    const float* __restrict__ x,
    const float* __restrict__ g_w, const float* __restrict__ g_b,
    const float* __restrict__ th_w, const float* __restrict__ th_b,
    const float* __restrict__ ph_w, const float* __restrict__ ph_b,
    const float* __restrict__ cp_wt, const float* __restrict__ cp_wp,
    float* __restrict__ ws)
{
    __shared__ float gw[CI*C];      // [i][c] (row-major, c contiguous)
    __shared__ float tw[C], pw[C];
    __shared__ float gb[CI];
    __shared__ float tpb[2];
    const int tid = threadIdx.x;
    const int blk = blockIdx.x;     // b*9 + ntile
    const int b  = blk / 9;
    const int n0 = (blk % 9) * 256;

    for (int i = tid; i < CI*C; i += 256) gw[i] = g_w[i];
    if (tid < C) {
        float s = 0.f;
        for (int i = 0; i < CI; i++) s += cp_wt[i] * th_w[i*C + tid];
        tw[tid] = s;
    } else if (tid < 2*C) {
        int c = tid - C; float s = 0.f;
        for (int i = 0; i < CI; i++) s += cp_wp[i] * ph_w[i*C + c];
        pw[c] = s;
    } else if (tid < 2*C + CI) {
        gb[tid - 2*C] = g_b[tid - 2*C];
    } else if (tid == 2*C + CI) {
        float s = 0.f; for (int i = 0; i < CI; i++) s += cp_wt[i]*th_b[i]; tpb[0] = s;
    } else if (tid == 2*C + CI + 1) {
        float s = 0.f; for (int i = 0; i < CI; i++) s += cp_wp[i]*ph_b[i]; tpb[1] = s;
    }
    if (blk == 0 && tid < 128) ((double*)(ws + OFF_STAT))[tid] = 0.0;  // zero BN stats each call
    __syncthreads();

    const int n = n0 + tid;
    float accg[CI];
    #pragma unroll
    for (int i = 0; i < CI; i++) accg[i] = 0.f;
    float aa = 0.f, cc = 0.f;
    const float* xb = x + (size_t)b*C*N + n;
    #pragma unroll 4
    for (int c4 = 0; c4 < C; c4 += 4) {
        float xv0 = xb[(size_t)(c4+0)*N];          // coalesced
        float xv1 = xb[(size_t)(c4+1)*N];
        float xv2 = xb[(size_t)(c4+2)*N];
        float xv3 = xb[(size_t)(c4+3)*N];
        float4 t4 = *(const float4*)(tw + c4);
        float4 p4 = *(const float4*)(pw + c4);
        aa += t4.x*xv0 + t4.y*xv1 + t4.z*xv2 + t4.w*xv3;
        cc += p4.x*xv0 + p4.y*xv1 + p4.z*xv2 + p4.w*xv3;
        #pragma unroll
        for (int i = 0; i < CI; i++) {
            float4 g4 = *(const float4*)(gw + i*C + c4);   // b128 broadcast
            accg[i] += g4.x*xv0 + g4.y*xv1 + g4.z*xv2 + g4.w*xv3;
        }
    }
    float* gx = ws + OFF_GX + ((size_t)(b*N + n))*CI;
    #pragma unroll
    for (int i = 0; i < CI; i++) accg[i] += gb[i];
    #pragma unroll
    for (int i = 0; i < CI; i += 4)
        *(float4*)(gx + i) = make_float4(accg[i], accg[i+1], accg[i+2], accg[i+3]);
    ws[OFF_A + b*N + n] = aa + tpb[0];
    ws[OFF_C + b*N + n] = cc + tpb[1];
}

// ------------------------------------------------------------------
// K2: rank-by-counting with u64 keys. key = ord(c)<<12 | (4095-j), where
// ord() is the order-preserving float->uint map. key_j > key_m  <=>
// (c_j > c_m) || (c_j == c_m && j < m). Single u64 compare per element.
// Grid: B*36 blocks; block handles 64 m's; wave q scans j-quarter q.
__global__ __launch_bounds__(256) void k_rank(float* __restrict__ ws)
{
    __shared__ __align__(16) unsigned long long keys[N];   // 18 KB
    __shared__ int partial[256];
    const int tid = threadIdx.x;
    const int blk = blockIdx.x;      // b*36 + mtile
    const int b  = blk / 36;
    const int m0 = (blk % 36) * 64;
    const float* cb = ws + OFF_C + b*N;
    for (int i = tid; i < N; i += 256) {
        unsigned int u = __float_as_uint(cb[i]);
        unsigned int k32 = (u & 0x80000000u) ? ~u : (u | 0x80000000u);
        keys[i] = ((unsigned long long)k32 << 12) | (unsigned long long)(4095 - i);
    }
    __syncthreads();
    const int mloc = tid & 63;
    const int q    = tid >> 6;                 // wave id = j-quarter
    const unsigned long long my = keys[m0 + mloc];
    const ulonglong2* kp = (const ulonglong2*)keys;
    int c0 = 0, c1 = 0, c2 = 0, c3 = 0;
    const int base = q * (N/8);                // N/2 ulonglong2 per batch / 4 waves
    #pragma unroll 8
    for (int t = 0; t < N/8; t += 2) {         // 2 x ulonglong2 per iter
        ulonglong2 ka = kp[base + t];
        ulonglong2 kb = kp[base + t + 1];
        c0 += (ka.x > my); c1 += (ka.y > my);
        c2 += (kb.x > my); c3 += (kb.y > my);
    }
    partial[tid] = (c0 + c1) + (c2 + c3);
    __syncthreads();
    if (tid < 64) {
        int rank = partial[tid] + partial[tid+64] + partial[tid+128] + partial[tid+192];
        unsigned long long km = keys[m0 + tid];
        unsigned int k32 = (unsigned int)(km >> 12);
        unsigned int u = (k32 & 0x80000000u) ? (k32 & 0x7fffffffu) : ~k32;
        ws[OFF_SC + b*N + rank] = __uint_as_float(u);
        ((int*)(ws + OFF_SIDX))[b*N + rank] = m0 + tid;
    }
}

// ------------------------------------------------------------------
// K3: per (batch, tile of 64 sorted positions): exclusive in-tile prefix of
//     [g[m,i] ; c_m*g[m,i]] (64 channels), + tile totals.
__global__ __launch_bounds__(64) void k_prefix(float* __restrict__ ws)
{
    __shared__ int   sidx[64];
    __shared__ float scv[64];
    const int tid = threadIdx.x;          // channel 0..63
    const int blk = blockIdx.x;           // b*NT + t
    const int b = blk / NT, t = blk % NT;
    const int k0 = t * 64;
    sidx[tid] = ((const int*)(ws + OFF_SIDX))[b*N + k0 + tid];
    scv[tid]  = ws[OFF_SC + b*N + k0 + tid];
    __syncthreads();
    const float* gx = ws + OFF_GX + (size_t)b*N*CI;
    float* pl = ws + OFF_PLOC + ((size_t)b*N + k0)*64;
    const int  ch   = tid & 31;
    const bool isCG = tid >= 32;
    float acc = 0.f;
    #pragma unroll
    for (int k = 0; k < 64; k++) {
        int m = sidx[k];                               // uniform
        float gval = gx[(size_t)m*CI + ch];            // 128B gather, 2-way broadcast
        float v = isCG ? gval * scv[k] : gval;
        pl[(size_t)k*64 + tid] = acc;                  // exclusive prefix
        acc += v;
    }
    ws[OFF_TOT + ((size_t)b*NT + t)*64 + tid] = acc;
}

// ------------------------------------------------------------------
// stage sorted-c + tile-offset scan, recompute y for a 64-position tile
// into LDS. Block = 256 thr: p=tid&63, ig=tid>>6 (8 ch each).
__device__ __forceinline__ void stage_and_y(
    const float* __restrict__ ws, int b, int tile,
    float* sc_lds, float* offs_lds /*(NT+1)*64*/, float* y_lds /*[64][33]*/)
{
    const int tid = threadIdx.x;
    const float* sc = ws + OFF_SC + b*N;
    for (int i = tid; i < N; i += 256) sc_lds[i] = sc[i];
    if (tid < 64) {                                    // exclusive scan of tile totals
        const float* tot = ws + OFF_TOT + (size_t)b*NT*64 + tid;
        float acc = 0.f;
        for (int t = 0; t < NT; t++) { offs_lds[t*64 + tid] = acc; acc += tot[(size_t)t*64]; }
        offs_lds[NT*64 + tid] = acc;
    }
    __syncthreads();

    const int p = tid & 63, ig = tid >> 6;
    const int n = tile*64 + p;
    const float an = ws[OFF_A + b*N + n];
    const float thr = -an;
    int lo = 0, hi = N;                                // count of sc[] > thr (desc order)
    while (lo < hi) { int mid = (lo + hi) >> 1; if (sc_lds[mid] > thr) lo = mid + 1; else hi = mid; }
    const int k = lo, kt = k >> 6;
    const float* pl = ws + OFF_PLOC + ((size_t)b*N + k)*64;
    const float inv_n = 1.0f / (float)N;
    #pragma unroll
    for (int q = 0; q < 8; q++) {
        int i = ig*8 + q;
        float plg = (k < N) ? pl[i]      : 0.f;
        float plc = (k < N) ? pl[i + 32] : 0.f;
        float Pg = offs_lds[kt*64 + i]      + plg;
        float Pc = offs_lds[kt*64 + i + 32] + plc;
        y_lds[p*33 + i] = inv_n * (an * Pg + Pc);
    }
}

// ------------------------------------------------------------------
// K4: BN batch stats: wy = W·y + W_b, accumulate Σwy, Σwy² per channel.
// Also writes y back to OFF_GX (gx dead after k_prefix) for k_final.
__global__ __launch_bounds__(256) void k_stats(
    const float* __restrict__ W_w, const float* __restrict__ W_b,
    float* __restrict__ ws)
{
    __shared__ float sc_lds[N];
    __shared__ float offs_lds[(NT+1)*64];
    __shared__ float y_lds[64*33];
    __shared__ float Wl[C*CI];
    const int tid = threadIdx.x;
    const int blk = blockIdx.x;
    const int b = blk / NT, tile = blk % NT;
    for (int i = tid; i < C*CI; i += 256) Wl[i] = W_w[i];
    stage_and_y(ws, b, tile, sc_lds, offs_lds, y_lds);
    __syncthreads();

    // write y tile back to GX region: y[b][tile*64+p][i]
    {
        float* yg = ws + OFF_GX + ((size_t)(b*N + tile*64))*CI;
        const int i0 = tid*8, p = i0 >> 5, i = i0 & 31;
        const float* src = y_lds + p*33 + i;
        ((float4*)yg)[tid*2]   = make_float4(src[0], src[1], src[2], src[3]);
        ((float4*)yg)[tid*2+1] = make_float4(src[4], src[5], src[6], src[7]);
    }

    const int p = tid & 63, cg = tid >> 6, lane = tid & 63;
    double* stats = (double*)(ws + OFF_STAT);
    for (int q = 0; q < 16; q++) {
        int c = cg*16 + q;
        float wyv = W_b[c];
        #pragma unroll
        for (int i4 = 0; i4 < CI; i4 += 4) {
            float4 w4 = *(const float4*)(Wl + c*CI + i4);   // b128 broadcast
            wyv += w4.x*y_lds[p*33 + i4]   + w4.y*y_lds[p*33 + i4+1]
                 + w4.z*y_lds[p*33 + i4+2] + w4.w*y_lds[p*33 + i4+3];
        }
        double s = (double)wyv, sq = (double)wyv * (double)wyv;
        #pragma unroll
        for (int off = 32; off >= 1; off >>= 1) {
            s  += __shfl_xor(s,  off, 64);
            sq += __shfl_xor(sq, off, 64);
        }
        if (lane == 0) { atomicAdd(&stats[c], s); atomicAdd(&stats[64 + c], sq); }
    }
}

// ------------------------------------------------------------------
// K5: finalize: read y tile (from GX region), wy = W·y + W_b, BN, +x.
__global__ __launch_bounds__(256) void k_final(
    const float* __restrict__ x,
    const float* __restrict__ W_w, const float* __restrict__ W_b,
    const float* __restrict__ bn_g, const float* __restrict__ bn_b,
    const float* __restrict__ ws, float* __restrict__ out)
{
    __shared__ float y_lds[64*33];
    __shared__ float Wl[C*CI];
    __shared__ float scale[C], shift[C];
    const int tid = threadIdx.x;
    const int blk = blockIdx.x;
    const int b = blk / NT, tile = blk % NT;
    for (int i = tid; i < C*CI; i += 256) Wl[i] = W_w[i];
    if (tid < C) {
        const double* stats = (const double*)(ws + OFF_STAT);
        double mean = stats[tid] / (double)NTOT;
        double var  = stats[64 + tid] / (double)NTOT - mean*mean;
        float rs = (float)(1.0 / sqrt(var + BN_EPS));
        float s  = bn_g[tid] * rs;
        scale[tid] = s;
        shift[tid] = bn_b[tid] - (float)mean * s;
    }
    {   // stage y tile: 2048 floats, float4 global reads, padded LDS writes
        const float* yg = ws + OFF_GX + ((size_t)(b*N + tile*64))*CI;
        float4 v0 = ((const float4*)yg)[tid*2];
        float4 v1 = ((const float4*)yg)[tid*2+1];
        const int i0 = tid*8, p = i0 >> 5, i = i0 & 31;
        float* dst = y_lds + p*33 + i;
        dst[0]=v0.x; dst[1]=v0.y; dst[2]=v0.z; dst[3]=v0.w;
        dst[4]=v1.x; dst[5]=v1.y; dst[6]=v1.z; dst[7]=v1.w;
    }
    __syncthreads();

    const int p = tid & 63, cg = tid >> 6;
    const int n = tile*64 + p;
    const float* xb = x   + (size_t)b*C*N + n;
    float*       ob = out + (size_t)b*C*N + n;
    for (int q = 0; q < 16; q++) {
        int c = cg*16 + q;
        float wyv = W_b[c];
        #pragma unroll
        for (int i4 = 0; i4 < CI; i4 += 4) {
            float4 w4 = *(const float4*)(Wl + c*CI + i4);   // b128 broadcast
            wyv += w4.x*y_lds[p*33 + i4]   + w4.y*y_lds[p*33 + i4+1]
                 + w4.z*y_lds[p*33 + i4+2] + w4.w*y_lds[p*33 + i4+3];
        }
        ob[(size_t)c*N] = wyv * scale[c] + shift[c] + xb[(size_t)c*N];   // coalesced
    }
}

// ------------------------------------------------------------------
extern "C" void kernel_launch(void* const* d_in, const int* in_sizes, int n_in,
                              void* d_out, int out_size, void* d_ws, size_t ws_size,
                              hipStream_t stream)
{
    const float* x     = (const float*)d_in[0];
    const float* g_w   = (const float*)d_in[1];
    const float* g_b   = (const float*)d_in[2];
    const float* th_w  = (const float*)d_in[3];
    const float* th_b  = (const float*)d_in[4];
    const float* ph_w  = (const float*)d_in[5];
    const float* ph_b  = (const float*)d_in[6];
    const float* cp_wt = (const float*)d_in[7];
    const float* cp_wp = (const float*)d_in[8];
    const float* W_w   = (const float*)d_in[9];
    const float* W_b   = (const float*)d_in[10];
    const float* bn_g  = (const float*)d_in[11];
    const float* bn_b  = (const float*)d_in[12];
    float* ws  = (float*)d_ws;
    float* out = (float*)d_out;

    hipLaunchKernelGGL(k_proj,   dim3(B*9),  dim3(256), 0, stream,
                       x, g_w, g_b, th_w, th_b, ph_w, ph_b, cp_wt, cp_wp, ws);
    hipLaunchKernelGGL(k_rank,   dim3(B*36), dim3(256), 0, stream, ws);
    hipLaunchKernelGGL(k_prefix, dim3(B*NT), dim3(64),  0, stream, ws);
    hipLaunchKernelGGL(k_stats,  dim3(B*NT), dim3(256), 0, stream, W_w, W_b, ws);
    hipLaunchKernelGGL(k_final,  dim3(B*NT), dim3(256), 0, stream,
                       x, W_w, W_b, bn_g, bn_b, ws, out);
}

// Round 7
// 85.895 us; speedup vs baseline: 1.9826x; 1.3550x over previous
//
#include <hip/hip_runtime.h>
#include <math.h>

#define B 8
#define C 64
#define CI 32
#define N 2304        // 48*48
#define NT 36         // tiles of 64
#define NTOT (B*N)    // 18432
#define BN_EPS 1e-5

// ---- workspace layout (float offsets) ----
#define OFF_GX   0                      // [B][N][CI]  (k_proj: g_x; after k_stats: y)
#define OFF_A    (OFF_GX + B*N*CI)      // [B][N]
#define OFF_C    (OFF_A + B*N)          // [B][N]
#define OFF_SC   (OFF_C + B*N)          // [B][N] sorted desc
#define OFF_SIDX (OFF_SC + B*N)         // [B][N] int
#define OFF_PLOC (OFF_SIDX + B*N)       // [B][N][64] exclusive in-tile prefix (g | c*g)
#define OFF_TOT  (OFF_PLOC + B*N*64)    // [B][NT][64] tile totals
#define OFF_STAT (OFF_TOT + B*NT*64)    // double[128]: sum[64], sumsq[64]
#define OFF_PART (OFF_STAT + 256)       // [B*NT][128] f32 per-block partials

// ------------------------------------------------------------------
// K1: g_x[b,n,i] = g_w[i,:]·x[b,:,n] + g_b[i]
//     a[b,n] = tw·x[b,:,n] + tb   (tw[c]=Σ_i cp_wt[i] th_w[i,c])
//     c[b,n] = pw·x[b,:,n] + pb
__global__ __launch_bounds__(256) void k_proj(
    const float* __restrict__ x,
    const float* __restrict__ g_w, const float* __restrict__ g_b,
    const float* __restrict__ th_w, const float* __restrict__ th_b,
    const float* __restrict__ ph_w, const float* __restrict__ ph_b,
    const float* __restrict__ cp_wt, const float* __restrict__ cp_wp,
    float* __restrict__ ws)
{
    __shared__ float gw[CI*C];      // [i][c] (row-major, c contiguous)
    __shared__ float tw[C], pw[C];
    __shared__ float gb[CI];
    __shared__ float tpb[2];
    const int tid = threadIdx.x;
    const int blk = blockIdx.x;     // b*9 + ntile
    const int b  = blk / 9;
    const int n0 = (blk % 9) * 256;

    for (int i = tid; i < CI*C; i += 256) gw[i] = g_w[i];
    if (tid < C) {
        float s = 0.f;
        for (int i = 0; i < CI; i++) s += cp_wt[i] * th_w[i*C + tid];
        tw[tid] = s;
    } else if (tid < 2*C) {
        int c = tid - C; float s = 0.f;
        for (int i = 0; i < CI; i++) s += cp_wp[i] * ph_w[i*C + c];
        pw[c] = s;
    } else if (tid < 2*C + CI) {
        gb[tid - 2*C] = g_b[tid - 2*C];
    } else if (tid == 2*C + CI) {
        float s = 0.f; for (int i = 0; i < CI; i++) s += cp_wt[i]*th_b[i]; tpb[0] = s;
    } else if (tid == 2*C + CI + 1) {
        float s = 0.f; for (int i = 0; i < CI; i++) s += cp_wp[i]*ph_b[i]; tpb[1] = s;
    }
    __syncthreads();

    const int n = n0 + tid;
    float accg[CI];
    #pragma unroll
    for (int i = 0; i < CI; i++) accg[i] = 0.f;
    float aa = 0.f, cc = 0.f;
    const float* xb = x + (size_t)b*C*N + n;
    #pragma unroll 4
    for (int c4 = 0; c4 < C; c4 += 4) {
        float xv0 = xb[(size_t)(c4+0)*N];          // coalesced
        float xv1 = xb[(size_t)(c4+1)*N];
        float xv2 = xb[(size_t)(c4+2)*N];
        float xv3 = xb[(size_t)(c4+3)*N];
        float4 t4 = *(const float4*)(tw + c4);
        float4 p4 = *(const float4*)(pw + c4);
        aa += t4.x*xv0 + t4.y*xv1 + t4.z*xv2 + t4.w*xv3;
        cc += p4.x*xv0 + p4.y*xv1 + p4.z*xv2 + p4.w*xv3;
        #pragma unroll
        for (int i = 0; i < CI; i++) {
            float4 g4 = *(const float4*)(gw + i*C + c4);   // b128 broadcast
            accg[i] += g4.x*xv0 + g4.y*xv1 + g4.z*xv2 + g4.w*xv3;
        }
    }
    float* gx = ws + OFF_GX + ((size_t)(b*N + n))*CI;
    #pragma unroll
    for (int i = 0; i < CI; i++) accg[i] += gb[i];
    #pragma unroll
    for (int i = 0; i < CI; i += 4)
        *(float4*)(gx + i) = make_float4(accg[i], accg[i+1], accg[i+2], accg[i+3]);
    ws[OFF_A + b*N + n] = aa + tpb[0];
    ws[OFF_C + b*N + n] = cc + tpb[1];
}

// ------------------------------------------------------------------
// K2: rank-by-counting with u64 keys. key = ord(c)<<12 | (4095-j).
// key_j > key_m  <=>  (c_j > c_m) || (c_j == c_m && j < m).
__global__ __launch_bounds__(256) void k_rank(float* __restrict__ ws)
{
    __shared__ __align__(16) unsigned long long keys[N];   // 18 KB
    __shared__ int partial[256];
    const int tid = threadIdx.x;
    const int blk = blockIdx.x;      // b*36 + mtile
    const int b  = blk / 36;
    const int m0 = (blk % 36) * 64;
    const float* cb = ws + OFF_C + b*N;
    for (int i = tid; i < N; i += 256) {
        unsigned int u = __float_as_uint(cb[i]);
        unsigned int k32 = (u & 0x80000000u) ? ~u : (u | 0x80000000u);
        keys[i] = ((unsigned long long)k32 << 12) | (unsigned long long)(4095 - i);
    }
    __syncthreads();
    const int mloc = tid & 63;
    const int q    = tid >> 6;                 // wave id = j-quarter
    const unsigned long long my = keys[m0 + mloc];
    const ulonglong2* kp = (const ulonglong2*)keys;
    int c0 = 0, c1 = 0, c2 = 0, c3 = 0;
    const int base = q * (N/8);
    #pragma unroll 8
    for (int t = 0; t < N/8; t += 2) {         // 2 x ulonglong2 per iter
        ulonglong2 ka = kp[base + t];
        ulonglong2 kb = kp[base + t + 1];
        c0 += (ka.x > my); c1 += (ka.y > my);
        c2 += (kb.x > my); c3 += (kb.y > my);
    }
    partial[tid] = (c0 + c1) + (c2 + c3);
    __syncthreads();
    if (tid < 64) {
        int rank = partial[tid] + partial[tid+64] + partial[tid+128] + partial[tid+192];
        unsigned long long km = keys[m0 + tid];
        unsigned int k32 = (unsigned int)(km >> 12);
        unsigned int u = (k32 & 0x80000000u) ? (k32 & 0x7fffffffu) : ~k32;
        ws[OFF_SC + b*N + rank] = __uint_as_float(u);
        ((int*)(ws + OFF_SIDX))[b*N + rank] = m0 + tid;
    }
}

// ------------------------------------------------------------------
// K3: per (batch, tile of 64 sorted positions): exclusive in-tile prefix of
//     [g[m,i] ; c_m*g[m,i]] (64 channels), + tile totals.
__global__ __launch_bounds__(64) void k_prefix(float* __restrict__ ws)
{
    __shared__ int   sidx[64];
    __shared__ float scv[64];
    const int tid = threadIdx.x;          // channel 0..63
    const int blk = blockIdx.x;           // b*NT + t
    const int b = blk / NT, t = blk % NT;
    const int k0 = t * 64;
    sidx[tid] = ((const int*)(ws + OFF_SIDX))[b*N + k0 + tid];
    scv[tid]  = ws[OFF_SC + b*N + k0 + tid];
    __syncthreads();
    const float* gx = ws + OFF_GX + (size_t)b*N*CI;
    float* pl = ws + OFF_PLOC + ((size_t)b*N + k0)*64;
    const int  ch   = tid & 31;
    const bool isCG = tid >= 32;
    float acc = 0.f;
    #pragma unroll
    for (int k = 0; k < 64; k++) {
        int m = sidx[k];                               // uniform
        float gval = gx[(size_t)m*CI + ch];            // 128B gather, 2-way broadcast
        float v = isCG ? gval * scv[k] : gval;
        pl[(size_t)k*64 + tid] = acc;                  // exclusive prefix
        acc += v;
    }
    ws[OFF_TOT + ((size_t)b*NT + t)*64 + tid] = acc;
}

// ------------------------------------------------------------------
// K4: per (b,tile): compute y tile (binary search + prefix lookup), write y
// to GX region, and emit per-block BN partial sums (f32, NO atomics).
__global__ __launch_bounds__(256) void k_stats(
    const float* __restrict__ W_w, const float* __restrict__ W_b,
    float* __restrict__ ws)
{
    __shared__ float sc_lds[N];              // 9216 B
    __shared__ float offs_lds[(NT+1)*64];    // 9472 B
    __shared__ float y_lds[64*33];           // 8448 B
    __shared__ float Wl[C*CI];               // 8192 B
    __shared__ float Wbl[C];
    const int tid = threadIdx.x;
    const int blk = blockIdx.x;
    const int b = blk / NT, tile = blk % NT;

    for (int i = tid; i < C*CI; i += 256) Wl[i] = W_w[i];
    if (tid < C) Wbl[tid] = W_b[tid];
    {   // stage sorted-c and tile totals (coalesced)
        const float* sc = ws + OFF_SC + b*N;
        for (int i = tid; i < N; i += 256) sc_lds[i] = sc[i];
        const float* tot = ws + OFF_TOT + (size_t)b*NT*64;
        for (int i = tid; i < NT*64; i += 256) offs_lds[i] = tot[i];
    }
    __syncthreads();
    if (tid < 64) {   // in-LDS exclusive scan over tiles (per channel)
        float acc = 0.f;
        #pragma unroll 4
        for (int t = 0; t < NT; t++) {
            float v = offs_lds[t*64 + tid];
            offs_lds[t*64 + tid] = acc;
            acc += v;
        }
        offs_lds[NT*64 + tid] = acc;
    }
    __syncthreads();

    // y for this 64-position tile: p = position-in-tile, ig = channel-octet
    const int p = tid & 63, ig = tid >> 6;
    const int n = tile*64 + p;
    const float an = ws[OFF_A + b*N + n];
    const float thr = -an;
    int lo = 0, hi = N;                                // count of sc[] > thr
    while (lo < hi) { int mid = (lo + hi) >> 1; if (sc_lds[mid] > thr) lo = mid + 1; else hi = mid; }
    const int k = lo, kt = k >> 6;
    const float* pl = ws + OFF_PLOC + ((size_t)b*N + k)*64;
    const float inv_n = 1.0f / (float)N;
    #pragma unroll
    for (int q = 0; q < 8; q++) {
        int i = ig*8 + q;
        float plg = (k < N) ? pl[i]      : 0.f;
        float plc = (k < N) ? pl[i + 32] : 0.f;
        float Pg = offs_lds[kt*64 + i]      + plg;
        float Pc = offs_lds[kt*64 + i + 32] + plc;
        y_lds[p*33 + i] = inv_n * (an * Pg + Pc);
    }
    __syncthreads();

    // write y tile back to GX region (gx dead after k_prefix) for k_final
    {
        float* yg = ws + OFF_GX + ((size_t)(b*N + tile*64))*CI;
        const int i0 = tid*8, pp = i0 >> 5, ii = i0 & 31;
        const float* src = y_lds + pp*33 + ii;
        ((float4*)yg)[tid*2]   = make_float4(src[0], src[1], src[2], src[3]);
        ((float4*)yg)[tid*2+1] = make_float4(src[4], src[5], src[6], src[7]);
    }

    // hoist y[p][0..31] to registers (stride-33 -> conflict-free)
    float yv[CI];
    #pragma unroll
    for (int i = 0; i < CI; i++) yv[i] = y_lds[p*33 + i];

    const int cg = tid >> 6, lane = tid & 63;
    float* part = ws + OFF_PART + (size_t)blk*128;
    for (int q = 0; q < 16; q++) {
        int c = cg*16 + q;                             // wave-uniform
        float wyv = Wbl[c];
        #pragma unroll
        for (int i4 = 0; i4 < CI; i4 += 4) {
            float4 w4 = *(const float4*)(Wl + c*CI + i4);   // b128 broadcast
            wyv += w4.x*yv[i4] + w4.y*yv[i4+1] + w4.z*yv[i4+2] + w4.w*yv[i4+3];
        }
        float s = wyv, sq = wyv * wyv;
        #pragma unroll
        for (int off = 32; off >= 1; off >>= 1) {
            s  += __shfl_xor(s,  off, 64);
            sq += __shfl_xor(sq, off, 64);
        }
        if (lane == 0) { part[c] = s; part[64 + c] = sq; }
    }
}

// ------------------------------------------------------------------
// K4b: reduce 288 per-block partials -> double stats (1 block, no atomics)
__global__ __launch_bounds__(128) void k_reduce(float* __restrict__ ws)
{
    const int tid = threadIdx.x;
    const float* part = ws + OFF_PART;
    double acc = 0.0;
    #pragma unroll 8
    for (int blk = 0; blk < B*NT; blk++)
        acc += (double)part[(size_t)blk*128 + tid];    // coalesced
    ((double*)(ws + OFF_STAT))[tid] = acc;
}

// ------------------------------------------------------------------
// K5: finalize: read y tile (from GX region), wy = W·y + W_b, BN, +x.
__global__ __launch_bounds__(256) void k_final(
    const float* __restrict__ x,
    const float* __restrict__ W_w, const float* __restrict__ W_b,
    const float* __restrict__ bn_g, const float* __restrict__ bn_b,
    const float* __restrict__ ws, float* __restrict__ out)
{
    __shared__ float y_lds[64*33];
    __shared__ float Wl[C*CI];
    __shared__ float Wbl[C];
    __shared__ float scale[C], shift[C];
    const int tid = threadIdx.x;
    const int blk = blockIdx.x;
    const int b = blk / NT, tile = blk % NT;
    for (int i = tid; i < C*CI; i += 256) Wl[i] = W_w[i];
    if (tid < C) {
        Wbl[tid] = W_b[tid];
        const double* stats = (const double*)(ws + OFF_STAT);
        double mean = stats[tid] / (double)NTOT;
        double var  = stats[64 + tid] / (double)NTOT - mean*mean;
        float rs = (float)(1.0 / sqrt(var + BN_EPS));
        float s  = bn_g[tid] * rs;
        scale[tid] = s;
        shift[tid] = bn_b[tid] - (float)mean * s;
    }
    {   // stage y tile: 2048 floats, float4 global reads, padded LDS writes
        const float* yg = ws + OFF_GX + ((size_t)(b*N + tile*64))*CI;
        float4 v0 = ((const float4*)yg)[tid*2];
        float4 v1 = ((const float4*)yg)[tid*2+1];
        const int i0 = tid*8, pp = i0 >> 5, ii = i0 & 31;
        float* dst = y_lds + pp*33 + ii;
        dst[0]=v0.x; dst[1]=v0.y; dst[2]=v0.z; dst[3]=v0.w;
        dst[4]=v1.x; dst[5]=v1.y; dst[6]=v1.z; dst[7]=v1.w;
    }
    __syncthreads();

    const int p = tid & 63, cg = tid >> 6;
    float yv[CI];
    #pragma unroll
    for (int i = 0; i < CI; i++) yv[i] = y_lds[p*33 + i];   // conflict-free

    const int n = tile*64 + p;
    const float* xb = x   + (size_t)b*C*N + n;
    float*       ob = out + (size_t)b*C*N + n;
    for (int q = 0; q < 16; q++) {
        int c = cg*16 + q;                             // wave-uniform
        float wyv = Wbl[c];
        #pragma unroll
        for (int i4 = 0; i4 < CI; i4 += 4) {
            float4 w4 = *(const float4*)(Wl + c*CI + i4);   // b128 broadcast
            wyv += w4.x*yv[i4] + w4.y*yv[i4+1] + w4.z*yv[i4+2] + w4.w*yv[i4+3];
        }
        ob[(size_t)c*N] = wyv * scale[c] + shift[c] + xb[(size_t)c*N];   // coalesced
    }
}

// ------------------------------------------------------------------
extern "C" void kernel_launch(void* const* d_in, const int* in_sizes, int n_in,
                              void* d_out, int out_size, void* d_ws, size_t ws_size,
                              hipStream_t stream)
{
    const float* x     = (const float*)d_in[0];
    const float* g_w   = (const float*)d_in[1];
    const float* g_b   = (const float*)d_in[2];
    const float* th_w  = (const float*)d_in[3];
    const float* th_b  = (const float*)d_in[4];
    const float* ph_w  = (const float*)d_in[5];
    const float* ph_b  = (const float*)d_in[6];
    const float* cp_wt = (const float*)d_in[7];
    const float* cp_wp = (const float*)d_in[8];
    const float* W_w   = (const float*)d_in[9];
    const float* W_b   = (const float*)d_in[10];
    const float* bn_g  = (const float*)d_in[11];
    const float* bn_b  = (const float*)d_in[12];
    float* ws  = (float*)d_ws;
    float* out = (float*)d_out;

    hipLaunchKernelGGL(k_proj,   dim3(B*9),  dim3(256), 0, stream,
                       x, g_w, g_b, th_w, th_b, ph_w, ph_b, cp_wt, cp_wp, ws);
    hipLaunchKernelGGL(k_rank,   dim3(B*36), dim3(256), 0, stream, ws);
    hipLaunchKernelGGL(k_prefix, dim3(B*NT), dim3(64),  0, stream, ws);
    hipLaunchKernelGGL(k_stats,  dim3(B*NT), dim3(256), 0, stream, W_w, W_b, ws);
    hipLaunchKernelGGL(k_reduce, dim3(1),    dim3(128), 0, stream, ws);
    hipLaunchKernelGGL(k_final,  dim3(B*NT), dim3(256), 0, stream,
                       x, W_w, W_b, bn_g, bn_b, ws, out);
}

// Round 8
// 68.797 us; speedup vs baseline: 2.4754x; 1.2485x over previous
//
#include <hip/hip_runtime.h>
#include <math.h>

#define B 8
#define C 64
#define CI 32
#define N 2304        // 48*48
#define NT 36         // tiles of 64
#define NTOT (B*N)    // 18432
#define BN_EPS 1e-5

// ---- workspace layout (float offsets) ----
#define OFF_GX   0                      // [B][N][CI] g_x
#define OFF_A    (OFF_GX + B*N*CI)      // [B][N]
#define OFF_C    (OFF_A + B*N)          // [B][N]
#define OFF_SC   (OFF_C + B*N)          // [B][N] sorted desc
#define OFF_SIDX (OFF_SC + B*N)         // [B][N] int
#define OFF_PLOC (OFF_SIDX + B*N)       // [B][N][64] exclusive in-tile prefix (g | c*g)
#define OFF_TOT  (OFF_PLOC + B*N*64)    // [B][NT][64] tile totals
#define OFF_STAT (OFF_TOT + B*NT*64)    // double[128]: sum[64], sumsq[64]
#define OFF_PART (OFF_STAT + 256)       // [B*NT][128] f32 per-block partials
#define OFF_WY   (OFF_PART + B*NT*128)  // [B][C][N] wy (pre-BN)

// ------------------------------------------------------------------
// K1: 288 blocks x 256 thr. Block = (b, 64-position tile). Thread (p, ig):
// position n0+p, g-channels [ig*8, ig*8+8); wave0 also a, wave1 also c.
__global__ __launch_bounds__(256) void k_proj(
    const float* __restrict__ x,
    const float* __restrict__ g_w, const float* __restrict__ g_b,
    const float* __restrict__ th_w, const float* __restrict__ th_b,
    const float* __restrict__ ph_w, const float* __restrict__ ph_b,
    const float* __restrict__ cp_wt, const float* __restrict__ cp_wp,
    float* __restrict__ ws)
{
    __shared__ float gw[CI*C];      // [i][c] (c contiguous)
    __shared__ float tw[C], pw[C];
    __shared__ float gb[CI];
    __shared__ float tpb[2];
    const int tid = threadIdx.x;
    const int blk = blockIdx.x;     // b*36 + t
    const int b  = blk / NT;
    const int n0 = (blk % NT) * 64;

    for (int i = tid; i < CI*C; i += 256) gw[i] = g_w[i];
    if (tid < C) {
        float s = 0.f;
        for (int i = 0; i < CI; i++) s += cp_wt[i] * th_w[i*C + tid];
        tw[tid] = s;
    } else if (tid < 2*C) {
        int c = tid - C; float s = 0.f;
        for (int i = 0; i < CI; i++) s += cp_wp[i] * ph_w[i*C + c];
        pw[c] = s;
    } else if (tid < 2*C + CI) {
        gb[tid - 2*C] = g_b[tid - 2*C];
    } else if (tid == 2*C + CI) {
        float s = 0.f; for (int i = 0; i < CI; i++) s += cp_wt[i]*th_b[i]; tpb[0] = s;
    } else if (tid == 2*C + CI + 1) {
        float s = 0.f; for (int i = 0; i < CI; i++) s += cp_wp[i]*ph_b[i]; tpb[1] = s;
    }
    __syncthreads();

    const int p = tid & 63, ig = tid >> 6;
    const int n = n0 + p;
    const int ch0 = ig*8;
    const float* xb = x + (size_t)b*C*N + n;
    float accg[8];
    #pragma unroll
    for (int j = 0; j < 8; j++) accg[j] = 0.f;
    float aa = 0.f, cc = 0.f;
    #pragma unroll 4
    for (int c4 = 0; c4 < C; c4 += 4) {
        float xv0 = xb[(size_t)(c4+0)*N];          // coalesced over p
        float xv1 = xb[(size_t)(c4+1)*N];
        float xv2 = xb[(size_t)(c4+2)*N];
        float xv3 = xb[(size_t)(c4+3)*N];
        if (ig == 0) {                              // wave-uniform branch
            float4 t4 = *(const float4*)(tw + c4);
            aa += t4.x*xv0 + t4.y*xv1 + t4.z*xv2 + t4.w*xv3;
        } else if (ig == 1) {
            float4 p4 = *(const float4*)(pw + c4);
            cc += p4.x*xv0 + p4.y*xv1 + p4.z*xv2 + p4.w*xv3;
        }
        #pragma unroll
        for (int j = 0; j < 8; j++) {
            float4 g4 = *(const float4*)(gw + (ch0+j)*C + c4);   // b128 broadcast
            accg[j] += g4.x*xv0 + g4.y*xv1 + g4.z*xv2 + g4.w*xv3;
        }
    }
    #pragma unroll
    for (int j = 0; j < 8; j++) accg[j] += gb[ch0 + j];
    float* gxp = ws + OFF_GX + ((size_t)(b*N + n))*CI + ch0;
    *(float4*)(gxp)     = make_float4(accg[0], accg[1], accg[2], accg[3]);
    *(float4*)(gxp + 4) = make_float4(accg[4], accg[5], accg[6], accg[7]);
    if (ig == 0) ws[OFF_A + b*N + n] = aa + tpb[0];
    else if (ig == 1) ws[OFF_C + b*N + n] = cc + tpb[1];
}

// ------------------------------------------------------------------
// K2: rank-by-counting with u64 keys. key = ord(c)<<12 | (4095-j).
// key_j > key_m  <=>  (c_j > c_m) || (c_j == c_m && j < m).
__global__ __launch_bounds__(256) void k_rank(float* __restrict__ ws)
{
    __shared__ __align__(16) unsigned long long keys[N];   // 18 KB
    __shared__ int partial[256];
    const int tid = threadIdx.x;
    const int blk = blockIdx.x;      // b*36 + mtile
    const int b  = blk / 36;
    const int m0 = (blk % 36) * 64;
    const float* cb = ws + OFF_C + b*N;
    for (int i = tid; i < N; i += 256) {
        unsigned int u = __float_as_uint(cb[i]);
        unsigned int k32 = (u & 0x80000000u) ? ~u : (u | 0x80000000u);
        keys[i] = ((unsigned long long)k32 << 12) | (unsigned long long)(4095 - i);
    }
    __syncthreads();
    const int mloc = tid & 63;
    const int q    = tid >> 6;                 // wave id = j-quarter
    const unsigned long long my = keys[m0 + mloc];
    const ulonglong2* kp = (const ulonglong2*)keys;
    int c0 = 0, c1 = 0, c2 = 0, c3 = 0;
    const int base = q * (N/8);
    #pragma unroll 8
    for (int t = 0; t < N/8; t += 2) {         // 2 x ulonglong2 per iter
        ulonglong2 ka = kp[base + t];
        ulonglong2 kb = kp[base + t + 1];
        c0 += (ka.x > my); c1 += (ka.y > my);
        c2 += (kb.x > my); c3 += (kb.y > my);
    }
    partial[tid] = (c0 + c1) + (c2 + c3);
    __syncthreads();
    if (tid < 64) {
        int rank = partial[tid] + partial[tid+64] + partial[tid+128] + partial[tid+192];
        unsigned long long km = keys[m0 + tid];
        unsigned int k32 = (unsigned int)(km >> 12);
        unsigned int u = (k32 & 0x80000000u) ? (k32 & 0x7fffffffu) : ~k32;
        ws[OFF_SC + b*N + rank] = __uint_as_float(u);
        ((int*)(ws + OFF_SIDX))[b*N + rank] = m0 + tid;
    }
}

// ------------------------------------------------------------------
// K3: 256 thr, two-level scan. Wave w does a 16-step local prefix of
// [g[m,i] ; c_m*g[m,i]] (64 channels) into LDS; segment offsets recombine.
__global__ __launch_bounds__(256) void k_prefix(float* __restrict__ ws)
{
    __shared__ int   sidx[64];
    __shared__ float scv[64];
    __shared__ float pl_lds[64*64];      // [k][ch] local exclusive prefix (16 KB)
    __shared__ float wtot[4*64];         // per-segment totals
    __shared__ float segoff[4*64];       // exclusive scan of wtot
    const int tid = threadIdx.x;
    const int blk = blockIdx.x;          // b*NT + t
    const int b = blk / NT, t = blk % NT;
    const int k0 = t * 64;
    if (tid < 64) {
        sidx[tid] = ((const int*)(ws + OFF_SIDX))[b*N + k0 + tid];
        scv[tid]  = ws[OFF_SC + b*N + k0 + tid];
    }
    __syncthreads();
    const int w   = tid >> 6;            // k-segment
    const int ch  = tid & 63;
    const int chm = ch & 31;
    const bool isCG = ch >= 32;
    const float* gx = ws + OFF_GX + (size_t)b*N*CI;
    float acc = 0.f;
    #pragma unroll
    for (int kk = 0; kk < 16; kk++) {
        int k = w*16 + kk;
        int m = sidx[k];                               // uniform in wave
        float gval = gx[(size_t)m*CI + chm];           // 128B gather, 2-way bcast
        float v = isCG ? gval * scv[k] : gval;
        pl_lds[k*64 + ch] = acc;
        acc += v;
    }
    wtot[w*64 + ch] = acc;
    __syncthreads();
    if (tid < 64) {
        float s = 0.f;
        #pragma unroll
        for (int ww = 0; ww < 4; ww++) { segoff[ww*64 + tid] = s; s += wtot[ww*64 + tid]; }
        ws[OFF_TOT + ((size_t)b*NT + t)*64 + tid] = s;     // tile total
    }
    __syncthreads();
    float* pl = ws + OFF_PLOC + ((size_t)b*N + k0)*64;
    #pragma unroll
    for (int r4 = 0; r4 < 16; r4++) {
        int r = (tid >> 6) + r4*4;
        pl[(size_t)r*64 + ch] = pl_lds[r*64 + ch] + segoff[(r >> 4)*64 + ch];
    }
}

// ------------------------------------------------------------------
// K4: per (b,tile): y via binary search + prefix lookup; wy = W·y + W_b
// stored to OFF_WY; per-block BN partials (f32, no atomics).
__global__ __launch_bounds__(256) void k_stats(
    const float* __restrict__ W_w, const float* __restrict__ W_b,
    float* __restrict__ ws)
{
    __shared__ float sc_lds[N];              // 9216 B
    __shared__ float offs_lds[(NT+1)*64];    // 9472 B
    __shared__ float y_lds[64*33];           // 8448 B
    __shared__ float Wl[C*CI];               // 8192 B
    __shared__ float Wbl[C];
    const int tid = threadIdx.x;
    const int blk = blockIdx.x;
    const int b = blk / NT, tile = blk % NT;

    for (int i = tid; i < C*CI; i += 256) Wl[i] = W_w[i];
    if (tid < C) Wbl[tid] = W_b[tid];
    {   // stage sorted-c and tile totals (coalesced)
        const float* sc = ws + OFF_SC + b*N;
        for (int i = tid; i < N; i += 256) sc_lds[i] = sc[i];
        const float* tot = ws + OFF_TOT + (size_t)b*NT*64;
        for (int i = tid; i < NT*64; i += 256) offs_lds[i] = tot[i];
    }
    __syncthreads();
    if (tid < 64) {   // in-LDS exclusive scan over tiles (per channel)
        float acc = 0.f;
        #pragma unroll 4
        for (int t = 0; t < NT; t++) {
            float v = offs_lds[t*64 + tid];
            offs_lds[t*64 + tid] = acc;
            acc += v;
        }
        offs_lds[NT*64 + tid] = acc;
    }
    __syncthreads();

    const int p = tid & 63, ig = tid >> 6;
    const int n = tile*64 + p;
    const float an = ws[OFF_A + b*N + n];
    const float thr = -an;
    int lo = 0, hi = N;                                // count of sc[] > thr
    while (lo < hi) { int mid = (lo + hi) >> 1; if (sc_lds[mid] > thr) lo = mid + 1; else hi = mid; }
    const int k = lo, kt = k >> 6;
    const float* pl = ws + OFF_PLOC + ((size_t)b*N + k)*64;
    const float inv_n = 1.0f / (float)N;
    #pragma unroll
    for (int q = 0; q < 8; q++) {
        int i = ig*8 + q;
        float plg = (k < N) ? pl[i]      : 0.f;
        float plc = (k < N) ? pl[i + 32] : 0.f;
        float Pg = offs_lds[kt*64 + i]      + plg;
        float Pc = offs_lds[kt*64 + i + 32] + plc;
        y_lds[p*33 + i] = inv_n * (an * Pg + Pc);
    }
    __syncthreads();

    // hoist y[p][0..31] to registers (stride-33 -> conflict-free)
    float yv[CI];
    #pragma unroll
    for (int i = 0; i < CI; i++) yv[i] = y_lds[p*33 + i];

    const int cg = tid >> 6, lane = tid & 63;
    float* part = ws + OFF_PART + (size_t)blk*128;
    float* wyb  = ws + OFF_WY + (size_t)b*C*N + n;
    for (int q = 0; q < 16; q++) {
        int c = cg*16 + q;                             // wave-uniform
        float wyv = Wbl[c];
        #pragma unroll
        for (int i4 = 0; i4 < CI; i4 += 4) {
            float4 w4 = *(const float4*)(Wl + c*CI + i4);   // b128 broadcast
            wyv += w4.x*yv[i4] + w4.y*yv[i4+1] + w4.z*yv[i4+2] + w4.w*yv[i4+3];
        }
        wyb[(size_t)c*N] = wyv;                        // coalesced over lanes
        float s = wyv, sq = wyv * wyv;
        #pragma unroll
        for (int off = 32; off >= 1; off >>= 1) {
            s  += __shfl_xor(s,  off, 64);
            sq += __shfl_xor(sq, off, 64);
        }
        if (lane == 0) { part[c] = s; part[64 + c] = sq; }
    }
}

// ------------------------------------------------------------------
// K4b: reduce 288 per-block partials -> double stats (1 block, no atomics)
__global__ __launch_bounds__(128) void k_reduce(float* __restrict__ ws)
{
    const int tid = threadIdx.x;
    const float* part = ws + OFF_PART;
    double acc = 0.0;
    #pragma unroll 8
    for (int blk = 0; blk < B*NT; blk++)
        acc += (double)part[(size_t)blk*128 + tid];    // coalesced
    ((double*)(ws + OFF_STAT))[tid] = acc;
}

// ------------------------------------------------------------------
// K5: pure streaming: out = wy*scale[c] + shift[c] + x. float4, c wave-uniform.
__global__ __launch_bounds__(256) void k_final(
    const float* __restrict__ x,
    const float* __restrict__ bn_g, const float* __restrict__ bn_b,
    const float* __restrict__ ws, float* __restrict__ out)
{
    __shared__ float scale[C], shift[C];
    const int tid = threadIdx.x;
    if (tid < C) {
        const double* stats = (const double*)(ws + OFF_STAT);
        double mean = stats[tid] / (double)NTOT;
        double var  = stats[64 + tid] / (double)NTOT - mean*mean;
        float rs = (float)(1.0 / sqrt(var + BN_EPS));
        float s  = bn_g[tid] * rs;
        scale[tid] = s;
        shift[tid] = bn_b[tid] - (float)mean * s;
    }
    __syncthreads();
    const int idx = blockIdx.x*256 + tid;              // float4 index
    const float4 w4 = ((const float4*)(ws + OFF_WY))[idx];
    const float4 x4 = ((const float4*)x)[idx];
    const int c = ((idx*4) / N) & 63;                  // wave-uniform (N%256==0)
    const float s = scale[c], sh = shift[c];
    float4 o;
    o.x = w4.x*s + sh + x4.x;
    o.y = w4.y*s + sh + x4.y;
    o.z = w4.z*s + sh + x4.z;
    o.w = w4.w*s + sh + x4.w;
    ((float4*)out)[idx] = o;
}

// ------------------------------------------------------------------
extern "C" void kernel_launch(void* const* d_in, const int* in_sizes, int n_in,
                              void* d_out, int out_size, void* d_ws, size_t ws_size,
                              hipStream_t stream)
{
    const float* x     = (const float*)d_in[0];
    const float* g_w   = (const float*)d_in[1];
    const float* g_b   = (const float*)d_in[2];
    const float* th_w  = (const float*)d_in[3];
    const float* th_b  = (const float*)d_in[4];
    const float* ph_w  = (const float*)d_in[5];
    const float* ph_b  = (const float*)d_in[6];
    const float* cp_wt = (const float*)d_in[7];
    const float* cp_wp = (const float*)d_in[8];
    const float* W_w   = (const float*)d_in[9];
    const float* W_b   = (const float*)d_in[10];
    const float* bn_g  = (const float*)d_in[11];
    const float* bn_b  = (const float*)d_in[12];
    float* ws  = (float*)d_ws;
    float* out = (float*)d_out;

    hipLaunchKernelGGL(k_proj,   dim3(B*NT), dim3(256), 0, stream,
                       x, g_w, g_b, th_w, th_b, ph_w, ph_b, cp_wt, cp_wp, ws);
    hipLaunchKernelGGL(k_rank,   dim3(B*NT), dim3(256), 0, stream, ws);
    hipLaunchKernelGGL(k_prefix, dim3(B*NT), dim3(256), 0, stream, ws);
    hipLaunchKernelGGL(k_stats,  dim3(B*NT), dim3(256), 0, stream, W_w, W_b, ws);
    hipLaunchKernelGGL(k_reduce, dim3(1),    dim3(128), 0, stream, ws);
    hipLaunchKernelGGL(k_final,  dim3(B*C*N/1024), dim3(256), 0, stream,
                       x, bn_g, bn_b, ws, out);
}